// Round 1
// baseline (294.692 us; speedup 1.0000x reference)
//
#include <hip/hip_runtime.h>

typedef __bf16 bf16x8 __attribute__((ext_vector_type(8)));
typedef float f32x4 __attribute__((ext_vector_type(4)));

__device__ __forceinline__ unsigned short f2bf(float f) {
  unsigned int u = __builtin_bit_cast(unsigned int, f);
  unsigned int r = (u + 0x7fffu + ((u >> 16) & 1u)) >> 16;
  return (unsigned short)r;
}

// ---------------- pre-pass kernels ----------------

__global__ __launch_bounds__(256) void cvt_f32_bf16(
    const float* __restrict__ in, unsigned short* __restrict__ out, int n4) {
  int i = blockIdx.x * 256 + threadIdx.x;
  if (i < n4) {
    float4 f = ((const float4*)in)[i];
    uint2 o;
    o.x = (unsigned)f2bf(f.x) | ((unsigned)f2bf(f.y) << 16);
    o.y = (unsigned)f2bf(f.z) | ((unsigned)f2bf(f.w) << 16);
    ((uint2*)out)[i] = o;
  }
}

// W [K,N] fp32 -> Wt [N,K] bf16
__global__ __launch_bounds__(256) void transpose_cvt(
    const float* __restrict__ W, unsigned short* __restrict__ Wt, int K, int N) {
  __shared__ float tile[32][33];
  int n0 = blockIdx.x * 32, k0 = blockIdx.y * 32;
  int tx = threadIdx.x, ty = threadIdx.y;
  #pragma unroll
  for (int r = 0; r < 32; r += 8)
    tile[ty + r][tx] = W[(size_t)(k0 + ty + r) * N + n0 + tx];
  __syncthreads();
  #pragma unroll
  for (int r = 0; r < 32; r += 8)
    Wt[(size_t)(n0 + ty + r) * K + k0 + tx] = f2bf(tile[tx][ty + r]);
}

// W3 [2048,50] fp32 -> W3t [64,2048] bf16, zero-padded rows 50..63
__global__ __launch_bounds__(256) void build_w3t(
    const float* __restrict__ W3, unsigned short* __restrict__ W3t) {
  int idx = blockIdx.x * 256 + threadIdx.x;  // 64*2048
  int n = idx >> 11;
  int k = idx & 2047;
  float v = (n < 50) ? W3[(size_t)k * 50 + n] : 0.f;
  W3t[idx] = f2bf(v);
}

// ---------------- main GEMMs: C = relu(A @ Bt^T + bias), bf16 in/out ----------------
// A [M,K] bf16 row-major, Bt [N,K] bf16 row-major. Block tile 128x128, BK=32.

__global__ __launch_bounds__(256) void gemm_bt_relu(
    const unsigned short* __restrict__ A,
    const unsigned short* __restrict__ Bt,
    const float* __restrict__ bias,
    unsigned short* __restrict__ C,
    int N, int K) {
  __shared__ __align__(16) unsigned short As[128 * 32];
  __shared__ __align__(16) unsigned short Bs[128 * 32];
  const int t = threadIdx.x;
  const int m0 = blockIdx.y * 128;
  const int n0 = blockIdx.x * 128;
  const int lane = t & 63, wave = t >> 6;
  const int l16 = lane & 15, quad = lane >> 4;
  const int wm = (wave >> 1) * 64, wn = (wave & 1) * 64;
  const int srow = t >> 1;
  const int scol = (t & 1) * 16;

  f32x4 acc[4][4] = {};

  const unsigned short* Aptr = A + (size_t)(m0 + srow) * K + scol;
  const unsigned short* Bptr = Bt + (size_t)(n0 + srow) * K + scol;
  uint4* AsW = (uint4*)&As[srow * 32 + scol];
  uint4* BsW = (uint4*)&Bs[srow * 32 + scol];

  for (int k0 = 0; k0 < K; k0 += 32) {
    const uint4* ag = (const uint4*)(Aptr + k0);
    const uint4* bg = (const uint4*)(Bptr + k0);
    uint4 a0 = ag[0], a1 = ag[1];
    uint4 b0 = bg[0], b1 = bg[1];
    AsW[0] = a0; AsW[1] = a1;
    BsW[0] = b0; BsW[1] = b1;
    __syncthreads();
    bf16x8 af[4], bfr[4];
    #pragma unroll
    for (int mi = 0; mi < 4; ++mi)
      af[mi] = *(const bf16x8*)&As[(wm + mi * 16 + l16) * 32 + quad * 8];
    #pragma unroll
    for (int ni = 0; ni < 4; ++ni)
      bfr[ni] = *(const bf16x8*)&Bs[(wn + ni * 16 + l16) * 32 + quad * 8];
    #pragma unroll
    for (int mi = 0; mi < 4; ++mi)
      #pragma unroll
      for (int ni = 0; ni < 4; ++ni)
        acc[mi][ni] = __builtin_amdgcn_mfma_f32_16x16x32_bf16(
            af[mi], bfr[ni], acc[mi][ni], 0, 0, 0);
    __syncthreads();
  }

  #pragma unroll
  for (int mi = 0; mi < 4; ++mi) {
    #pragma unroll
    for (int ni = 0; ni < 4; ++ni) {
      int col = n0 + wn + ni * 16 + l16;
      float bv = bias[col];
      #pragma unroll
      for (int r = 0; r < 4; ++r) {
        int row = m0 + wm + mi * 16 + quad * 4 + r;
        float v = acc[mi][ni][r] + bv;
        v = fmaxf(v, 0.f);
        C[(size_t)row * N + col] = f2bf(v);
      }
    }
  }
}

// ---------------- GEMM3: out3[8192,50] = h2 @ W3 + b3, split-K=4, atomic ----------------
// A [8192,2048] bf16, Bt = W3t [64,2048] bf16. Block tile 128x64, BK=32.

__global__ __launch_bounds__(256) void gemm3_splitk(
    const unsigned short* __restrict__ A,
    const unsigned short* __restrict__ Bt,
    const float* __restrict__ bias,
    float* __restrict__ out3) {
  __shared__ __align__(16) unsigned short As[128 * 32];
  __shared__ __align__(16) unsigned short Bs[64 * 32];
  const int t = threadIdx.x;
  const int m0 = blockIdx.x * 128;
  const int kz = blockIdx.y;
  const int lane = t & 63, wave = t >> 6;
  const int l16 = lane & 15, quad = lane >> 4;
  const int wm = wave * 32;
  const int srow = t >> 1, scol = (t & 1) * 16;
  const int brow = t >> 2, bcol = (t & 3) * 8;

  f32x4 acc[2][4] = {};

  const unsigned short* Aptr = A + (size_t)(m0 + srow) * 2048 + kz * 512 + scol;
  const unsigned short* Bptr = Bt + (size_t)brow * 2048 + kz * 512 + bcol;
  uint4* AsW = (uint4*)&As[srow * 32 + scol];
  uint4* BsW = (uint4*)&Bs[brow * 32 + bcol];

  for (int k0 = 0; k0 < 512; k0 += 32) {
    const uint4* ag = (const uint4*)(Aptr + k0);
    uint4 a0 = ag[0], a1 = ag[1];
    uint4 b0 = ((const uint4*)(Bptr + k0))[0];
    AsW[0] = a0; AsW[1] = a1;
    BsW[0] = b0;
    __syncthreads();
    bf16x8 af[2], bfr[4];
    #pragma unroll
    for (int mi = 0; mi < 2; ++mi)
      af[mi] = *(const bf16x8*)&As[(wm + mi * 16 + l16) * 32 + quad * 8];
    #pragma unroll
    for (int ni = 0; ni < 4; ++ni)
      bfr[ni] = *(const bf16x8*)&Bs[(ni * 16 + l16) * 32 + quad * 8];
    #pragma unroll
    for (int mi = 0; mi < 2; ++mi)
      #pragma unroll
      for (int ni = 0; ni < 4; ++ni)
        acc[mi][ni] = __builtin_amdgcn_mfma_f32_16x16x32_bf16(
            af[mi], bfr[ni], acc[mi][ni], 0, 0, 0);
    __syncthreads();
  }

  #pragma unroll
  for (int mi = 0; mi < 2; ++mi) {
    #pragma unroll
    for (int ni = 0; ni < 4; ++ni) {
      int col = ni * 16 + l16;
      if (col < 50) {
        #pragma unroll
        for (int r = 0; r < 4; ++r) {
          int row = m0 + wm + mi * 16 + quad * 4 + r;
          float v = acc[mi][ni][r];
          if (kz == 0) v += bias[col];
          atomicAdd(&out3[(size_t)row * 50 + col], v);
        }
      }
    }
  }
}

// ---------------- geometry: homography solve + warp + fold ----------------
// 16 batches per block; 1 thread per (batch, patch).

__global__ __launch_bounds__(256) void geometry_kernel(
    const float* __restrict__ out3, float* __restrict__ outp) {
  __shared__ float fold[16 * 578];  // [16][2][17][17]
  const int t = threadIdx.x;
  const int bbase = blockIdx.x * 16;
  for (int i = t; i < 16 * 578; i += 256) fold[i] = 0.f;
  __syncthreads();

  const int bl = t >> 4;
  const int p = t & 15;
  const int pi = p >> 2, pj = p & 3;
  const float* o = out3 + (size_t)(bbase + bl) * 50;

  // build 8x8 system for 4-point homography (exact reference layout)
  float Am[8][9];
  #pragma unroll
  for (int c = 0; c < 4; ++c) {
    int r = pi + (c >> 1);
    int cc = pj + (c & 1);
    float xs = 128.f * r;
    float ys = 128.f * cc;
    float uu = xs + o[r * 5 + cc];
    float vv = ys + o[25 + r * 5 + cc];
    float* r0 = Am[c];
    r0[0] = xs; r0[1] = ys; r0[2] = 1.f; r0[3] = 0.f; r0[4] = 0.f; r0[5] = 0.f;
    r0[6] = -uu * xs; r0[7] = -uu * ys; r0[8] = uu;
    float* r1 = Am[c + 4];
    r1[0] = 0.f; r1[1] = 0.f; r1[2] = 0.f; r1[3] = xs; r1[4] = ys; r1[5] = 1.f;
    r1[6] = -vv * xs; r1[7] = -vv * ys; r1[8] = vv;
  }
  // gaussian elimination with partial pivoting
  for (int col = 0; col < 8; ++col) {
    int pr = col;
    float best = fabsf(Am[col][col]);
    for (int r = col + 1; r < 8; ++r) {
      float cand = fabsf(Am[r][col]);
      if (cand > best) { best = cand; pr = r; }
    }
    if (pr != col) {
      for (int j = col; j < 9; ++j) {
        float tmp = Am[col][j]; Am[col][j] = Am[pr][j]; Am[pr][j] = tmp;
      }
    }
    float inv = 1.f / Am[col][col];
    for (int r = col + 1; r < 8; ++r) {
      float f = Am[r][col] * inv;
      for (int j = col + 1; j < 9; ++j) Am[r][j] -= f * Am[col][j];
    }
  }
  float h[8];
  for (int r = 7; r >= 0; --r) {
    float s = Am[r][8];
    for (int j = r + 1; j < 8; ++j) s -= Am[r][j] * h[j];
    h[r] = s / Am[r][r];
  }

  // warp the 5x5 dense sub-grid of this patch, accumulate into fold
  #pragma unroll
  for (int a = 0; a < 5; ++a) {
    #pragma unroll
    for (int bb = 0; bb < 5; ++bb) {
      int gi = pi * 4 + a, gj = pj * 4 + bb;
      float X = 32.f * gi, Y = 32.f * gj;
      float rden = 1.f / (h[6] * X + h[7] * Y + 1.f);
      float xx = (h[0] * X + h[1] * Y + h[2]) * rden;
      float yy = (h[3] * X + h[4] * Y + h[5]) * rden;
      atomicAdd(&fold[(bl * 2 + 0) * 289 + gi * 17 + gj], xx);
      atomicAdd(&fold[(bl * 2 + 1) * 289 + gi * 17 + gj], yy);
    }
  }
  __syncthreads();

  // rescale crossing points, subtract dense grid, write out
  for (int i = t; i < 16 * 578; i += 256) {
    int blb = i / 578;
    int rem = i - blb * 578;
    int ch = rem / 289;
    int ij = rem - ch * 289;
    int gi = ij / 17, gj = ij - gi * 17;
    float val = fold[i];
    if ((gi % 4 == 0) && (gj % 4 == 0)) val *= 0.5f;
    if ((gi == 0 || gi == 16) && (gj == 0 || gj == 16)) val *= 2.f;
    val -= (ch == 0) ? 32.f * gi : 32.f * gj;
    outp[(size_t)(bbase + blb) * 578 + rem] = val;
  }
}

// ---------------- launch ----------------

extern "C" void kernel_launch(void* const* d_in, const int* in_sizes, int n_in,
                              void* d_out, int out_size, void* d_ws, size_t ws_size,
                              hipStream_t stream) {
  const float* x  = (const float*)d_in[0];
  const float* W1 = (const float*)d_in[1];
  const float* b1 = (const float*)d_in[2];
  const float* W2 = (const float*)d_in[3];
  const float* b2 = (const float*)d_in[4];
  const float* W3 = (const float*)d_in[5];
  const float* b3 = (const float*)d_in[6];
  float* outp = (float*)d_out;

  char* ws = (char*)d_ws;
  size_t off = 0;
  auto alloc = [&](size_t bytes) {
    void* pp = ws + off;
    off += (bytes + 255) & ~(size_t)255;
    return pp;
  };
  unsigned short* xbf = (unsigned short*)alloc((size_t)8192 * 1024 * 2);
  unsigned short* w1t = (unsigned short*)alloc((size_t)1024 * 1024 * 2);
  unsigned short* w2t = (unsigned short*)alloc((size_t)2048 * 1024 * 2);
  unsigned short* w3t = (unsigned short*)alloc((size_t)64 * 2048 * 2);
  unsigned short* h1  = (unsigned short*)alloc((size_t)8192 * 1024 * 2);
  unsigned short* h2  = (unsigned short*)alloc((size_t)8192 * 2048 * 2);
  float* out3 = (float*)alloc((size_t)8192 * 50 * 4);

  hipMemsetAsync(out3, 0, (size_t)8192 * 50 * 4, stream);

  cvt_f32_bf16<<<8192, 256, 0, stream>>>(x, xbf, 8192 * 1024 / 4);
  transpose_cvt<<<dim3(1024 / 32, 1024 / 32), dim3(32, 8), 0, stream>>>(W1, w1t, 1024, 1024);
  transpose_cvt<<<dim3(2048 / 32, 1024 / 32), dim3(32, 8), 0, stream>>>(W2, w2t, 1024, 2048);
  build_w3t<<<512, 256, 0, stream>>>(W3, w3t);

  gemm_bt_relu<<<dim3(1024 / 128, 8192 / 128), 256, 0, stream>>>(xbf, w1t, b1, h1, 1024, 1024);
  gemm_bt_relu<<<dim3(2048 / 128, 8192 / 128), 256, 0, stream>>>(h1, w2t, b2, h2, 2048, 1024);
  gemm3_splitk<<<dim3(64, 4), 256, 0, stream>>>(h2, w3t, b3, out3);

  geometry_kernel<<<512, 256, 0, stream>>>(out3, outp);
}

// Round 2
// 257.225 us; speedup vs baseline: 1.1457x; 1.1457x over previous
//
#include <hip/hip_runtime.h>

typedef __bf16 bf16x8 __attribute__((ext_vector_type(8)));
typedef float f32x4 __attribute__((ext_vector_type(4)));

__device__ __forceinline__ unsigned short f2bf(float f) {
  unsigned int u = __builtin_bit_cast(unsigned int, f);
  unsigned int r = (u + 0x7fffu + ((u >> 16) & 1u)) >> 16;
  return (unsigned short)r;
}

__device__ __forceinline__ void load16_lds(const unsigned short* g, unsigned short* l) {
  __builtin_amdgcn_global_load_lds(
      (const __attribute__((address_space(1))) void*)g,
      (__attribute__((address_space(3))) void*)l, 16, 0, 0);
}

// ---------------- pre-pass kernels ----------------

__global__ __launch_bounds__(256) void cvt_f32_bf16(
    const float* __restrict__ in, unsigned short* __restrict__ out, int n4) {
  int i = blockIdx.x * 256 + threadIdx.x;
  if (i < n4) {
    float4 f = ((const float4*)in)[i];
    uint2 o;
    o.x = (unsigned)f2bf(f.x) | ((unsigned)f2bf(f.y) << 16);
    o.y = (unsigned)f2bf(f.z) | ((unsigned)f2bf(f.w) << 16);
    ((uint2*)out)[i] = o;
  }
}

// W [K,N] fp32 -> Wt [N,K] bf16
__global__ __launch_bounds__(256) void transpose_cvt(
    const float* __restrict__ W, unsigned short* __restrict__ Wt, int K, int N) {
  __shared__ float tile[32][33];
  int n0 = blockIdx.x * 32, k0 = blockIdx.y * 32;
  int tx = threadIdx.x, ty = threadIdx.y;
  #pragma unroll
  for (int r = 0; r < 32; r += 8)
    tile[ty + r][tx] = W[(size_t)(k0 + ty + r) * N + n0 + tx];
  __syncthreads();
  #pragma unroll
  for (int r = 0; r < 32; r += 8)
    Wt[(size_t)(n0 + ty + r) * K + k0 + tx] = f2bf(tile[tx][ty + r]);
}

// W3 [2048,50] fp32 -> W3t [64,2048] bf16, zero-padded rows 50..63
__global__ __launch_bounds__(256) void build_w3t(
    const float* __restrict__ W3, unsigned short* __restrict__ W3t) {
  int idx = blockIdx.x * 256 + threadIdx.x;  // 64*2048
  int n = idx >> 11;
  int k = idx & 2047;
  float v = (n < 50) ? W3[(size_t)k * 50 + n] : 0.f;
  W3t[idx] = f2bf(v);
}

// ---------------- main GEMMs: C = relu(A @ Bt^T + bias), bf16 in/out ----------------
// A [M,K] bf16 row-major, Bt [N,K] bf16 row-major. Block tile 128x128, BK=32.
// m97 structure: global_load_lds width=16 staging (wave-uniform base + lane*16).

__global__ __launch_bounds__(256) void gemm_bt_relu(
    const unsigned short* __restrict__ A,
    const unsigned short* __restrict__ Bt,
    const float* __restrict__ bias,
    unsigned short* __restrict__ C,
    int N, int K) {
  __shared__ __align__(16) unsigned short As[128 * 32];
  __shared__ __align__(16) unsigned short Bs[128 * 32];
  const int t = threadIdx.x;
  const int m0 = blockIdx.y * 128;
  const int n0 = blockIdx.x * 128;
  const int lane = t & 63, wv = t >> 6;
  const int l16 = lane & 15, quad = lane >> 4;
  const int wm = (wv >> 1) * 64, wn = (wv & 1) * 64;

  // staging map: thread t loads row=t>>2 (and +64), cols (t&3)*8 .. +8
  const int srow = t >> 2;
  const int scol = (t & 3) * 8;
  const unsigned short* Ag0 = A + (size_t)(m0 + srow) * K + scol;
  const unsigned short* Ag1 = Ag0 + (size_t)64 * K;
  const unsigned short* Bg0 = Bt + (size_t)(n0 + srow) * K + scol;
  const unsigned short* Bg1 = Bg0 + (size_t)64 * K;
  unsigned short* AsL0 = As + wv * 512;         // wave-uniform LDS bases
  unsigned short* AsL1 = As + 2048 + wv * 512;
  unsigned short* BsL0 = Bs + wv * 512;
  unsigned short* BsL1 = Bs + 2048 + wv * 512;

  f32x4 acc[4][4] = {};

  for (int k0 = 0; k0 < K; k0 += 32) {
    load16_lds(Ag0 + k0, AsL0);
    load16_lds(Ag1 + k0, AsL1);
    load16_lds(Bg0 + k0, BsL0);
    load16_lds(Bg1 + k0, BsL1);
    __syncthreads();
    bf16x8 af[4], bfr[4];
    #pragma unroll
    for (int mi = 0; mi < 4; ++mi)
      af[mi] = *(const bf16x8*)&As[(wm + mi * 16 + l16) * 32 + quad * 8];
    #pragma unroll
    for (int ni = 0; ni < 4; ++ni)
      bfr[ni] = *(const bf16x8*)&Bs[(wn + ni * 16 + l16) * 32 + quad * 8];
    #pragma unroll
    for (int mi = 0; mi < 4; ++mi)
      #pragma unroll
      for (int ni = 0; ni < 4; ++ni)
        acc[mi][ni] = __builtin_amdgcn_mfma_f32_16x16x32_bf16(
            af[mi], bfr[ni], acc[mi][ni], 0, 0, 0);
    __syncthreads();
  }

  #pragma unroll
  for (int mi = 0; mi < 4; ++mi) {
    #pragma unroll
    for (int ni = 0; ni < 4; ++ni) {
      int col = n0 + wn + ni * 16 + l16;
      float bv = bias[col];
      #pragma unroll
      for (int r = 0; r < 4; ++r) {
        int row = m0 + wm + mi * 16 + quad * 4 + r;
        float v = acc[mi][ni][r] + bv;
        v = fmaxf(v, 0.f);
        C[(size_t)row * N + col] = f2bf(v);
      }
    }
  }
}

// ---------------- GEMM3: out3[8192,50] = h2 @ W3 + b3, split-K=4, atomic ----------------
// A [8192,2048] bf16, Bt = W3t [64,2048] bf16. Block tile 128x64, BK=32.

__global__ __launch_bounds__(256) void gemm3_splitk(
    const unsigned short* __restrict__ A,
    const unsigned short* __restrict__ Bt,
    const float* __restrict__ bias,
    float* __restrict__ out3) {
  __shared__ __align__(16) unsigned short As[128 * 32];
  __shared__ __align__(16) unsigned short Bs[64 * 32];
  const int t = threadIdx.x;
  const int m0 = blockIdx.x * 128;
  const int kz = blockIdx.y;
  const int lane = t & 63, wv = t >> 6;
  const int l16 = lane & 15, quad = lane >> 4;
  const int wm = wv * 32;

  const int srow = t >> 2;
  const int scol = (t & 3) * 8;
  const unsigned short* Ag0 = A + (size_t)(m0 + srow) * 2048 + kz * 512 + scol;
  const unsigned short* Ag1 = Ag0 + (size_t)64 * 2048;
  const unsigned short* Bg  = Bt + (size_t)srow * 2048 + kz * 512 + scol;
  unsigned short* AsL0 = As + wv * 512;
  unsigned short* AsL1 = As + 2048 + wv * 512;
  unsigned short* BsL  = Bs + wv * 512;

  f32x4 acc[2][4] = {};

  for (int k0 = 0; k0 < 512; k0 += 32) {
    load16_lds(Ag0 + k0, AsL0);
    load16_lds(Ag1 + k0, AsL1);
    load16_lds(Bg + k0, BsL);
    __syncthreads();
    bf16x8 af[2], bfr[4];
    #pragma unroll
    for (int mi = 0; mi < 2; ++mi)
      af[mi] = *(const bf16x8*)&As[(wm + mi * 16 + l16) * 32 + quad * 8];
    #pragma unroll
    for (int ni = 0; ni < 4; ++ni)
      bfr[ni] = *(const bf16x8*)&Bs[(ni * 16 + l16) * 32 + quad * 8];
    #pragma unroll
    for (int mi = 0; mi < 2; ++mi)
      #pragma unroll
      for (int ni = 0; ni < 4; ++ni)
        acc[mi][ni] = __builtin_amdgcn_mfma_f32_16x16x32_bf16(
            af[mi], bfr[ni], acc[mi][ni], 0, 0, 0);
    __syncthreads();
  }

  #pragma unroll
  for (int mi = 0; mi < 2; ++mi) {
    #pragma unroll
    for (int ni = 0; ni < 4; ++ni) {
      int col = ni * 16 + l16;
      if (col < 50) {
        #pragma unroll
        for (int r = 0; r < 4; ++r) {
          int row = m0 + wm + mi * 16 + quad * 4 + r;
          float v = acc[mi][ni][r];
          if (kz == 0) v += bias[col];
          atomicAdd(&out3[(size_t)row * 50 + col], v);
        }
      }
    }
  }
}

// ---------------- geometry: closed-form homography + warp + fold ----------------
// 16 batches per block; 1 thread per (batch, patch). No arrays -> no scratch.

__global__ __launch_bounds__(256) void geometry_kernel(
    const float* __restrict__ out3, float* __restrict__ outp) {
  __shared__ float fold[16 * 578];  // [16][2][17][17]
  const int t = threadIdx.x;
  const int bbase = blockIdx.x * 16;
  for (int i = t; i < 16 * 578; i += 256) fold[i] = 0.f;
  __syncthreads();

  const int bl = t >> 4;
  const int p = t & 15;
  const int pi = p >> 2, pj = p & 3;
  const float* o = out3 + (size_t)(bbase + bl) * 50;

  // dst quad corners: u = 128*r + flowx, v = 128*c + flowy
  float u00 = 128.f * pi       + o[pi * 5 + pj];
  float v00 = 128.f * pj       + o[25 + pi * 5 + pj];
  float u01 = 128.f * pi       + o[pi * 5 + pj + 1];
  float v01 = 128.f * (pj + 1) + o[25 + pi * 5 + pj + 1];
  float u10 = 128.f * (pi + 1) + o[(pi + 1) * 5 + pj];
  float v10 = 128.f * pj       + o[25 + (pi + 1) * 5 + pj];
  float u11 = 128.f * (pi + 1) + o[(pi + 1) * 5 + pj + 1];
  float v11 = 128.f * (pj + 1) + o[25 + (pi + 1) * 5 + pj + 1];

  // Heckbert closed-form unit-square -> quad homography
  float sx = u00 - u10 + u11 - u01;
  float sy = v00 - v10 + v11 - v01;
  float dx1 = u10 - u11, dx2 = u01 - u11;
  float dy1 = v10 - v11, dy2 = v01 - v11;
  float rden = 1.f / (dx1 * dy2 - dx2 * dy1);
  float g = (sx * dy2 - dx2 * sy) * rden;
  float h = (dx1 * sy - sx * dy1) * rden;
  float a = u10 - u00 + g * u10;
  float b = u01 - u00 + h * u01;
  float c = u00;
  float d = v10 - v00 + g * v10;
  float e = v01 - v00 + h * v01;
  float f = v00;

  #pragma unroll
  for (int ai = 0; ai < 5; ++ai) {
    #pragma unroll
    for (int bi = 0; bi < 5; ++bi) {
      float s = 0.25f * ai, tt = 0.25f * bi;
      float rw = 1.f / (g * s + h * tt + 1.f);
      float xx = (a * s + b * tt + c) * rw;
      float yy = (d * s + e * tt + f) * rw;
      int gi = pi * 4 + ai, gj = pj * 4 + bi;
      atomicAdd(&fold[(bl * 2 + 0) * 289 + gi * 17 + gj], xx);
      atomicAdd(&fold[(bl * 2 + 1) * 289 + gi * 17 + gj], yy);
    }
  }
  __syncthreads();

  // rescale crossing points, subtract dense grid, write out
  for (int i = t; i < 16 * 578; i += 256) {
    int blb = i / 578;
    int rem = i - blb * 578;
    int ch = rem / 289;
    int ij = rem - ch * 289;
    int gi = ij / 17, gj = ij - gi * 17;
    float val = fold[i];
    if ((gi % 4 == 0) && (gj % 4 == 0)) val *= 0.5f;
    if ((gi == 0 || gi == 16) && (gj == 0 || gj == 16)) val *= 2.f;
    val -= (ch == 0) ? 32.f * gi : 32.f * gj;
    outp[(size_t)(bbase + blb) * 578 + rem] = val;
  }
}

// ---------------- launch ----------------

extern "C" void kernel_launch(void* const* d_in, const int* in_sizes, int n_in,
                              void* d_out, int out_size, void* d_ws, size_t ws_size,
                              hipStream_t stream) {
  const float* x  = (const float*)d_in[0];
  const float* W1 = (const float*)d_in[1];
  const float* b1 = (const float*)d_in[2];
  const float* W2 = (const float*)d_in[3];
  const float* b2 = (const float*)d_in[4];
  const float* W3 = (const float*)d_in[5];
  const float* b3 = (const float*)d_in[6];
  float* outp = (float*)d_out;

  char* ws = (char*)d_ws;
  size_t off = 0;
  auto alloc = [&](size_t bytes) {
    void* pp = ws + off;
    off += (bytes + 255) & ~(size_t)255;
    return pp;
  };
  unsigned short* xbf = (unsigned short*)alloc((size_t)8192 * 1024 * 2);
  unsigned short* w1t = (unsigned short*)alloc((size_t)1024 * 1024 * 2);
  unsigned short* w2t = (unsigned short*)alloc((size_t)2048 * 1024 * 2);
  unsigned short* w3t = (unsigned short*)alloc((size_t)64 * 2048 * 2);
  unsigned short* h1  = (unsigned short*)alloc((size_t)8192 * 1024 * 2);
  unsigned short* h2  = (unsigned short*)alloc((size_t)8192 * 2048 * 2);
  float* out3 = (float*)alloc((size_t)8192 * 50 * 4);

  hipMemsetAsync(out3, 0, (size_t)8192 * 50 * 4, stream);

  cvt_f32_bf16<<<8192, 256, 0, stream>>>(x, xbf, 8192 * 1024 / 4);
  transpose_cvt<<<dim3(1024 / 32, 1024 / 32), dim3(32, 8), 0, stream>>>(W1, w1t, 1024, 1024);
  transpose_cvt<<<dim3(2048 / 32, 1024 / 32), dim3(32, 8), 0, stream>>>(W2, w2t, 1024, 2048);
  build_w3t<<<512, 256, 0, stream>>>(W3, w3t);

  gemm_bt_relu<<<dim3(1024 / 128, 8192 / 128), 256, 0, stream>>>(xbf, w1t, b1, h1, 1024, 1024);
  gemm_bt_relu<<<dim3(2048 / 128, 8192 / 128), 256, 0, stream>>>(h1, w2t, b2, h2, 2048, 1024);
  gemm3_splitk<<<dim3(64, 4), 256, 0, stream>>>(h2, w3t, b3, out3);

  geometry_kernel<<<512, 256, 0, stream>>>(out3, outp);
}

// Round 3
// 230.830 us; speedup vs baseline: 1.2767x; 1.1143x over previous
//
#include <hip/hip_runtime.h>

typedef __bf16 bf16x8 __attribute__((ext_vector_type(8)));
typedef float f32x4 __attribute__((ext_vector_type(4)));

__device__ __forceinline__ unsigned short f2bf(float f) {
  unsigned int u = __builtin_bit_cast(unsigned int, f);
  unsigned int r = (u + 0x7fffu + ((u >> 16) & 1u)) >> 16;
  return (unsigned short)r;
}

__device__ __forceinline__ void load16_lds(const unsigned short* g, unsigned short* l) {
  __builtin_amdgcn_global_load_lds(
      (const __attribute__((address_space(1))) void*)g,
      (__attribute__((address_space(3))) void*)l, 16, 0, 0);
}

// ---------------- fused pre-pass: x cvt + W1/W2 transpose + W3t + zero(out3) ----------------

__global__ __launch_bounds__(256) void prepass(
    const float* __restrict__ x, const float* __restrict__ W1,
    const float* __restrict__ W2, const float* __restrict__ W3,
    unsigned short* __restrict__ xbf, unsigned short* __restrict__ w1t,
    unsigned short* __restrict__ w2t, unsigned short* __restrict__ w3t,
    float* __restrict__ out3) {
  __shared__ float tile[32][33];
  const int bid = blockIdx.x;
  const int t = threadIdx.x;
  if (bid < 2048) {
    // x [8192,1024] fp32 -> bf16 ; 2097152 float4 groups
    for (int i = bid * 256 + t; i < 2097152; i += 2048 * 256) {
      float4 f = ((const float4*)x)[i];
      uint2 o;
      o.x = (unsigned)f2bf(f.x) | ((unsigned)f2bf(f.y) << 16);
      o.y = (unsigned)f2bf(f.z) | ((unsigned)f2bf(f.w) << 16);
      ((uint2*)xbf)[i] = o;
    }
  } else if (bid < 3072) {
    // W1 [1024,1024] -> w1t [1024,1024] bf16 (transposed)
    int ti = bid - 2048;
    int n0 = (ti & 31) * 32, k0 = (ti >> 5) * 32;
    int tx = t & 31, ty = t >> 5;
    #pragma unroll
    for (int r = 0; r < 32; r += 8)
      tile[ty + r][tx] = W1[(size_t)(k0 + ty + r) * 1024 + n0 + tx];
    __syncthreads();
    #pragma unroll
    for (int r = 0; r < 32; r += 8)
      w1t[(size_t)(n0 + ty + r) * 1024 + k0 + tx] = f2bf(tile[tx][ty + r]);
  } else if (bid < 5120) {
    // W2 [1024,2048] -> w2t [2048,1024] bf16
    int ti = bid - 3072;
    int n0 = (ti & 63) * 32, k0 = (ti >> 6) * 32;
    int tx = t & 31, ty = t >> 5;
    #pragma unroll
    for (int r = 0; r < 32; r += 8)
      tile[ty + r][tx] = W2[(size_t)(k0 + ty + r) * 2048 + n0 + tx];
    __syncthreads();
    #pragma unroll
    for (int r = 0; r < 32; r += 8)
      w2t[(size_t)(n0 + ty + r) * 1024 + k0 + tx] = f2bf(tile[tx][ty + r]);
  } else if (bid < 5632) {
    // W3 [2048,50] -> w3t [64,2048] bf16, zero-padded
    int idx = (bid - 5120) * 256 + t;
    int n = idx >> 11, k = idx & 2047;
    w3t[idx] = f2bf((n < 50) ? W3[(size_t)k * 50 + n] : 0.f);
  } else {
    // zero out3 [8192,50] fp32 = 102400 float4
    int i = (bid - 5632) * 256 + t;
    if (i < 102400) ((float4*)out3)[i] = make_float4(0.f, 0.f, 0.f, 0.f);
  }
}

// ---------------- main GEMMs: C = relu(A @ Bt^T + bias), bf16 in/out ----------------
// A [M,K] bf16 row-major, Bt [N,K] bf16 row-major. Block tile 128x128, BK=64.
// m0 on blockIdx.x -> blocks sharing an A-slice land on one XCD (id%8 const).
// LDS layout XOR-swizzled: logical (row, colblk cb) stored at physblk = cb^(row&7)
// -> ds_read_b128 spreads all 8 bank groups (2-way alias = free).

__global__ __launch_bounds__(256) void gemm_bt_relu(
    const unsigned short* __restrict__ A,
    const unsigned short* __restrict__ Bt,
    const float* __restrict__ bias,
    unsigned short* __restrict__ C,
    int N, int K) {
  __shared__ __align__(16) unsigned short As[128 * 64];
  __shared__ __align__(16) unsigned short Bs[128 * 64];
  const int t = threadIdx.x;
  const int m0 = blockIdx.x * 128;
  const int n0 = blockIdx.y * 128;
  const int lane = t & 63, wv = t >> 6;
  const int l16 = lane & 15, quad = lane >> 4;
  const int wm = (wv >> 1) * 64, wn = (wv & 1) * 64;

  // staging: thread t covers (row = srow + 32r, logical colblk (t&7)^(srow&7))
  const int srow = t >> 3;
  const int scol = ((t & 7) ^ (srow & 7)) * 8;
  const unsigned short* Ag0 = A + (size_t)(m0 + srow) * K + scol;
  const unsigned short* Bg0 = Bt + (size_t)(n0 + srow) * K + scol;
  unsigned short* AsW = As + wv * 8 * 64;  // wave-uniform LDS base
  unsigned short* BsW = Bs + wv * 8 * 64;

  f32x4 acc[4][4] = {};

  for (int k0 = 0; k0 < K; k0 += 64) {
    #pragma unroll
    for (int r = 0; r < 4; ++r) {
      load16_lds(Ag0 + (size_t)(r * 32) * K + k0, AsW + r * 32 * 64);
      load16_lds(Bg0 + (size_t)(r * 32) * K + k0, BsW + r * 32 * 64);
    }
    __syncthreads();
    #pragma unroll
    for (int half = 0; half < 2; ++half) {
      bf16x8 af[4], bfr[4];
      #pragma unroll
      for (int mi = 0; mi < 4; ++mi) {
        int row = wm + mi * 16 + l16;
        int pb = (half * 4 + quad) ^ (row & 7);
        af[mi] = *(const bf16x8*)&As[row * 64 + pb * 8];
      }
      #pragma unroll
      for (int ni = 0; ni < 4; ++ni) {
        int row = wn + ni * 16 + l16;
        int pb = (half * 4 + quad) ^ (row & 7);
        bfr[ni] = *(const bf16x8*)&Bs[row * 64 + pb * 8];
      }
      #pragma unroll
      for (int mi = 0; mi < 4; ++mi)
        #pragma unroll
        for (int ni = 0; ni < 4; ++ni)
          acc[mi][ni] = __builtin_amdgcn_mfma_f32_16x16x32_bf16(
              af[mi], bfr[ni], acc[mi][ni], 0, 0, 0);
    }
    __syncthreads();
  }

  #pragma unroll
  for (int mi = 0; mi < 4; ++mi) {
    #pragma unroll
    for (int ni = 0; ni < 4; ++ni) {
      int col = n0 + wn + ni * 16 + l16;
      float bv = bias[col];
      #pragma unroll
      for (int r = 0; r < 4; ++r) {
        int row = m0 + wm + mi * 16 + quad * 4 + r;
        float v = acc[mi][ni][r] + bv;
        v = fmaxf(v, 0.f);
        C[(size_t)row * N + col] = f2bf(v);
      }
    }
  }
}

// ---------------- GEMM3: out3[8192,50] = h2 @ W3 + b3, split-K=4, atomic ----------------

__global__ __launch_bounds__(256) void gemm3_splitk(
    const unsigned short* __restrict__ A,
    const unsigned short* __restrict__ Bt,
    const float* __restrict__ bias,
    float* __restrict__ out3) {
  __shared__ __align__(16) unsigned short As[128 * 32];
  __shared__ __align__(16) unsigned short Bs[64 * 32];
  const int t = threadIdx.x;
  const int m0 = blockIdx.x * 128;
  const int kz = blockIdx.y;
  const int lane = t & 63, wv = t >> 6;
  const int l16 = lane & 15, quad = lane >> 4;
  const int wm = wv * 32;

  const int srow = t >> 2;
  const int scol = (t & 3) * 8;
  const unsigned short* Ag0 = A + (size_t)(m0 + srow) * 2048 + kz * 512 + scol;
  const unsigned short* Ag1 = Ag0 + (size_t)64 * 2048;
  const unsigned short* Bg  = Bt + (size_t)srow * 2048 + kz * 512 + scol;
  unsigned short* AsL0 = As + wv * 512;
  unsigned short* AsL1 = As + 2048 + wv * 512;
  unsigned short* BsL  = Bs + wv * 512;

  f32x4 acc[2][4] = {};

  for (int k0 = 0; k0 < 512; k0 += 32) {
    load16_lds(Ag0 + k0, AsL0);
    load16_lds(Ag1 + k0, AsL1);
    load16_lds(Bg + k0, BsL);
    __syncthreads();
    bf16x8 af[2], bfr[4];
    #pragma unroll
    for (int mi = 0; mi < 2; ++mi)
      af[mi] = *(const bf16x8*)&As[(wm + mi * 16 + l16) * 32 + quad * 8];
    #pragma unroll
    for (int ni = 0; ni < 4; ++ni)
      bfr[ni] = *(const bf16x8*)&Bs[(ni * 16 + l16) * 32 + quad * 8];
    #pragma unroll
    for (int mi = 0; mi < 2; ++mi)
      #pragma unroll
      for (int ni = 0; ni < 4; ++ni)
        acc[mi][ni] = __builtin_amdgcn_mfma_f32_16x16x32_bf16(
            af[mi], bfr[ni], acc[mi][ni], 0, 0, 0);
    __syncthreads();
  }

  #pragma unroll
  for (int mi = 0; mi < 2; ++mi) {
    #pragma unroll
    for (int ni = 0; ni < 4; ++ni) {
      int col = ni * 16 + l16;
      if (col < 50) {
        #pragma unroll
        for (int r = 0; r < 4; ++r) {
          int row = m0 + wm + mi * 16 + quad * 4 + r;
          float v = acc[mi][ni][r];
          if (kz == 0) v += bias[col];
          atomicAdd(&out3[(size_t)row * 50 + col], v);
        }
      }
    }
  }
}

// ---------------- geometry: closed-form homography + warp + fold ----------------

__global__ __launch_bounds__(256) void geometry_kernel(
    const float* __restrict__ out3, float* __restrict__ outp) {
  __shared__ float fold[16 * 578];  // [16][2][17][17]
  const int t = threadIdx.x;
  const int bbase = blockIdx.x * 16;
  for (int i = t; i < 16 * 578; i += 256) fold[i] = 0.f;
  __syncthreads();

  const int bl = t >> 4;
  const int p = t & 15;
  const int pi = p >> 2, pj = p & 3;
  const float* o = out3 + (size_t)(bbase + bl) * 50;

  float u00 = 128.f * pi       + o[pi * 5 + pj];
  float v00 = 128.f * pj       + o[25 + pi * 5 + pj];
  float u01 = 128.f * pi       + o[pi * 5 + pj + 1];
  float v01 = 128.f * (pj + 1) + o[25 + pi * 5 + pj + 1];
  float u10 = 128.f * (pi + 1) + o[(pi + 1) * 5 + pj];
  float v10 = 128.f * pj       + o[25 + (pi + 1) * 5 + pj];
  float u11 = 128.f * (pi + 1) + o[(pi + 1) * 5 + pj + 1];
  float v11 = 128.f * (pj + 1) + o[25 + (pi + 1) * 5 + pj + 1];

  // Heckbert closed-form unit-square -> quad homography
  float sx = u00 - u10 + u11 - u01;
  float sy = v00 - v10 + v11 - v01;
  float dx1 = u10 - u11, dx2 = u01 - u11;
  float dy1 = v10 - v11, dy2 = v01 - v11;
  float rden = 1.f / (dx1 * dy2 - dx2 * dy1);
  float g = (sx * dy2 - dx2 * sy) * rden;
  float h = (dx1 * sy - sx * dy1) * rden;
  float a = u10 - u00 + g * u10;
  float b = u01 - u00 + h * u01;
  float c = u00;
  float d = v10 - v00 + g * v10;
  float e = v01 - v00 + h * v01;
  float f = v00;

  #pragma unroll
  for (int ai = 0; ai < 5; ++ai) {
    #pragma unroll
    for (int bi = 0; bi < 5; ++bi) {
      float s = 0.25f * ai, tt = 0.25f * bi;
      float rw = 1.f / (g * s + h * tt + 1.f);
      float xx = (a * s + b * tt + c) * rw;
      float yy = (d * s + e * tt + f) * rw;
      int gi = pi * 4 + ai, gj = pj * 4 + bi;
      atomicAdd(&fold[(bl * 2 + 0) * 289 + gi * 17 + gj], xx);
      atomicAdd(&fold[(bl * 2 + 1) * 289 + gi * 17 + gj], yy);
    }
  }
  __syncthreads();

  for (int i = t; i < 16 * 578; i += 256) {
    int blb = i / 578;
    int rem = i - blb * 578;
    int ch = rem / 289;
    int ij = rem - ch * 289;
    int gi = ij / 17, gj = ij - gi * 17;
    float val = fold[i];
    if ((gi % 4 == 0) && (gj % 4 == 0)) val *= 0.5f;
    if ((gi == 0 || gi == 16) && (gj == 0 || gj == 16)) val *= 2.f;
    val -= (ch == 0) ? 32.f * gi : 32.f * gj;
    outp[(size_t)(bbase + blb) * 578 + rem] = val;
  }
}

// ---------------- launch ----------------

extern "C" void kernel_launch(void* const* d_in, const int* in_sizes, int n_in,
                              void* d_out, int out_size, void* d_ws, size_t ws_size,
                              hipStream_t stream) {
  const float* x  = (const float*)d_in[0];
  const float* W1 = (const float*)d_in[1];
  const float* b1 = (const float*)d_in[2];
  const float* W2 = (const float*)d_in[3];
  const float* b2 = (const float*)d_in[4];
  const float* W3 = (const float*)d_in[5];
  const float* b3 = (const float*)d_in[6];
  float* outp = (float*)d_out;

  char* ws = (char*)d_ws;
  size_t off = 0;
  auto alloc = [&](size_t bytes) {
    void* pp = ws + off;
    off += (bytes + 255) & ~(size_t)255;
    return pp;
  };
  unsigned short* xbf = (unsigned short*)alloc((size_t)8192 * 1024 * 2);
  unsigned short* w1t = (unsigned short*)alloc((size_t)1024 * 1024 * 2);
  unsigned short* w2t = (unsigned short*)alloc((size_t)2048 * 1024 * 2);
  unsigned short* w3t = (unsigned short*)alloc((size_t)64 * 2048 * 2);
  unsigned short* h1  = (unsigned short*)alloc((size_t)8192 * 1024 * 2);
  unsigned short* h2  = (unsigned short*)alloc((size_t)8192 * 2048 * 2);
  float* out3 = (float*)alloc((size_t)8192 * 50 * 4);

  prepass<<<6032, 256, 0, stream>>>(x, W1, W2, W3, xbf, w1t, w2t, w3t, out3);

  // m-index on blockIdx.x: same-A blocks differ by 64 in linear id -> same XCD
  gemm_bt_relu<<<dim3(64, 8), 256, 0, stream>>>(xbf, w1t, b1, h1, 1024, 1024);
  gemm_bt_relu<<<dim3(64, 16), 256, 0, stream>>>(h1, w2t, b2, h2, 2048, 1024);
  gemm3_splitk<<<dim3(64, 4), 256, 0, stream>>>(h2, w3t, b3, out3);

  geometry_kernel<<<512, 256, 0, stream>>>(out3, outp);
}

// Round 4
// 219.264 us; speedup vs baseline: 1.3440x; 1.0527x over previous
//
#include <hip/hip_runtime.h>

typedef __bf16 bf16x8 __attribute__((ext_vector_type(8)));
typedef float f32x4 __attribute__((ext_vector_type(4)));

__device__ __forceinline__ unsigned short f2bf(float f) {
  unsigned int u = __builtin_bit_cast(unsigned int, f);
  unsigned int r = (u + 0x7fffu + ((u >> 16) & 1u)) >> 16;
  return (unsigned short)r;
}

__device__ __forceinline__ void load16_lds(const unsigned short* g, unsigned short* l) {
  __builtin_amdgcn_global_load_lds(
      (const __attribute__((address_space(1))) void*)g,
      (__attribute__((address_space(3))) void*)l, 16, 0, 0);
}

// ---------------- fused pre-pass: x cvt + W1/W2 transpose + W3t ----------------

__global__ __launch_bounds__(256) void prepass(
    const float* __restrict__ x, const float* __restrict__ W1,
    const float* __restrict__ W2, const float* __restrict__ W3,
    unsigned short* __restrict__ xbf, unsigned short* __restrict__ w1t,
    unsigned short* __restrict__ w2t, unsigned short* __restrict__ w3t) {
  __shared__ float tile[32][33];
  const int bid = blockIdx.x;
  const int t = threadIdx.x;
  if (bid < 2048) {
    // x [8192,1024] fp32 -> bf16 ; 2097152 float4 groups
    for (int i = bid * 256 + t; i < 2097152; i += 2048 * 256) {
      float4 f = ((const float4*)x)[i];
      uint2 o;
      o.x = (unsigned)f2bf(f.x) | ((unsigned)f2bf(f.y) << 16);
      o.y = (unsigned)f2bf(f.z) | ((unsigned)f2bf(f.w) << 16);
      ((uint2*)xbf)[i] = o;
    }
  } else if (bid < 3072) {
    // W1 [1024,1024] -> w1t [1024,1024] bf16 (transposed)
    int ti = bid - 2048;
    int n0 = (ti & 31) * 32, k0 = (ti >> 5) * 32;
    int tx = t & 31, ty = t >> 5;
    #pragma unroll
    for (int r = 0; r < 32; r += 8)
      tile[ty + r][tx] = W1[(size_t)(k0 + ty + r) * 1024 + n0 + tx];
    __syncthreads();
    #pragma unroll
    for (int r = 0; r < 32; r += 8)
      w1t[(size_t)(n0 + ty + r) * 1024 + k0 + tx] = f2bf(tile[tx][ty + r]);
  } else if (bid < 5120) {
    // W2 [1024,2048] -> w2t [2048,1024] bf16
    int ti = bid - 3072;
    int n0 = (ti & 63) * 32, k0 = (ti >> 6) * 32;
    int tx = t & 31, ty = t >> 5;
    #pragma unroll
    for (int r = 0; r < 32; r += 8)
      tile[ty + r][tx] = W2[(size_t)(k0 + ty + r) * 2048 + n0 + tx];
    __syncthreads();
    #pragma unroll
    for (int r = 0; r < 32; r += 8)
      w2t[(size_t)(n0 + ty + r) * 1024 + k0 + tx] = f2bf(tile[tx][ty + r]);
  } else {
    // W3 [2048,50] -> w3t [64,2048] bf16, zero-padded
    int idx = (bid - 5120) * 256 + t;
    int n = idx >> 11, k = idx & 2047;
    w3t[idx] = f2bf((n < 50) ? W3[(size_t)k * 50 + n] : 0.f);
  }
}

// ---------------- GEMM (128x128): C = relu(A @ Bt^T + bias), bf16 in/out ----------------
// XOR-swizzled LDS (physblk = cb^(row&7)); global_load_lds width=16 staging.

__global__ __launch_bounds__(256) void gemm_bt_relu(
    const unsigned short* __restrict__ A,
    const unsigned short* __restrict__ Bt,
    const float* __restrict__ bias,
    unsigned short* __restrict__ C,
    int N, int K) {
  __shared__ __align__(16) unsigned short As[128 * 64];
  __shared__ __align__(16) unsigned short Bs[128 * 64];
  const int t = threadIdx.x;
  const int m0 = blockIdx.x * 128;
  const int n0 = blockIdx.y * 128;
  const int lane = t & 63, wv = t >> 6;
  const int l16 = lane & 15, quad = lane >> 4;
  const int wm = (wv >> 1) * 64, wn = (wv & 1) * 64;

  const int srow = t >> 3;
  const int scol = ((t & 7) ^ (srow & 7)) * 8;
  const unsigned short* Ag0 = A + (size_t)(m0 + srow) * K + scol;
  const unsigned short* Bg0 = Bt + (size_t)(n0 + srow) * K + scol;
  unsigned short* AsW = As + wv * 8 * 64;
  unsigned short* BsW = Bs + wv * 8 * 64;

  f32x4 acc[4][4] = {};

  for (int k0 = 0; k0 < K; k0 += 64) {
    #pragma unroll
    for (int r = 0; r < 4; ++r) {
      load16_lds(Ag0 + (size_t)(r * 32) * K + k0, AsW + r * 32 * 64);
      load16_lds(Bg0 + (size_t)(r * 32) * K + k0, BsW + r * 32 * 64);
    }
    __syncthreads();
    #pragma unroll
    for (int half = 0; half < 2; ++half) {
      bf16x8 af[4], bfr[4];
      #pragma unroll
      for (int mi = 0; mi < 4; ++mi) {
        int row = wm + mi * 16 + l16;
        int pb = (half * 4 + quad) ^ (row & 7);
        af[mi] = *(const bf16x8*)&As[row * 64 + pb * 8];
      }
      #pragma unroll
      for (int ni = 0; ni < 4; ++ni) {
        int row = wn + ni * 16 + l16;
        int pb = (half * 4 + quad) ^ (row & 7);
        bfr[ni] = *(const bf16x8*)&Bs[row * 64 + pb * 8];
      }
      #pragma unroll
      for (int mi = 0; mi < 4; ++mi)
        #pragma unroll
        for (int ni = 0; ni < 4; ++ni)
          acc[mi][ni] = __builtin_amdgcn_mfma_f32_16x16x32_bf16(
              af[mi], bfr[ni], acc[mi][ni], 0, 0, 0);
    }
    __syncthreads();
  }

  #pragma unroll
  for (int mi = 0; mi < 4; ++mi) {
    #pragma unroll
    for (int ni = 0; ni < 4; ++ni) {
      int col = n0 + wn + ni * 16 + l16;
      float bv = bias[col];
      #pragma unroll
      for (int r = 0; r < 4; ++r) {
        int row = m0 + wm + mi * 16 + quad * 4 + r;
        float v = acc[mi][ni][r] + bv;
        v = fmaxf(v, 0.f);
        C[(size_t)row * N + col] = f2bf(v);
      }
    }
  }
}

// ---------------- GEMM (128x64 n-tile) for GEMM1: more blocks when N is small ----

__global__ __launch_bounds__(256) void gemm_bt_relu_n64(
    const unsigned short* __restrict__ A,
    const unsigned short* __restrict__ Bt,
    const float* __restrict__ bias,
    unsigned short* __restrict__ C,
    int N, int K) {
  __shared__ __align__(16) unsigned short As[128 * 64];
  __shared__ __align__(16) unsigned short Bs[64 * 64];
  const int t = threadIdx.x;
  const int m0 = blockIdx.x * 128;
  const int n0 = blockIdx.y * 64;
  const int lane = t & 63, wv = t >> 6;
  const int l16 = lane & 15, quad = lane >> 4;
  const int wm = (wv >> 1) * 64, wn = (wv & 1) * 32;

  const int srow = t >> 3;
  const int scol = ((t & 7) ^ (srow & 7)) * 8;
  const unsigned short* Ag0 = A + (size_t)(m0 + srow) * K + scol;
  const unsigned short* Bg0 = Bt + (size_t)(n0 + srow) * K + scol;
  unsigned short* AsW = As + wv * 8 * 64;
  unsigned short* BsW = Bs + wv * 8 * 64;

  f32x4 acc[4][2] = {};

  for (int k0 = 0; k0 < K; k0 += 64) {
    #pragma unroll
    for (int r = 0; r < 4; ++r)
      load16_lds(Ag0 + (size_t)(r * 32) * K + k0, AsW + r * 32 * 64);
    #pragma unroll
    for (int r = 0; r < 2; ++r)
      load16_lds(Bg0 + (size_t)(r * 32) * K + k0, BsW + r * 32 * 64);
    __syncthreads();
    #pragma unroll
    for (int half = 0; half < 2; ++half) {
      bf16x8 af[4], bfr[2];
      #pragma unroll
      for (int mi = 0; mi < 4; ++mi) {
        int row = wm + mi * 16 + l16;
        int pb = (half * 4 + quad) ^ (row & 7);
        af[mi] = *(const bf16x8*)&As[row * 64 + pb * 8];
      }
      #pragma unroll
      for (int ni = 0; ni < 2; ++ni) {
        int row = wn + ni * 16 + l16;
        int pb = (half * 4 + quad) ^ (row & 7);
        bfr[ni] = *(const bf16x8*)&Bs[row * 64 + pb * 8];
      }
      #pragma unroll
      for (int mi = 0; mi < 4; ++mi)
        #pragma unroll
        for (int ni = 0; ni < 2; ++ni)
          acc[mi][ni] = __builtin_amdgcn_mfma_f32_16x16x32_bf16(
              af[mi], bfr[ni], acc[mi][ni], 0, 0, 0);
    }
    __syncthreads();
  }

  #pragma unroll
  for (int mi = 0; mi < 4; ++mi) {
    #pragma unroll
    for (int ni = 0; ni < 2; ++ni) {
      int col = n0 + wn + ni * 16 + l16;
      float bv = bias[col];
      #pragma unroll
      for (int r = 0; r < 4; ++r) {
        int row = m0 + wm + mi * 16 + quad * 4 + r;
        float v = acc[mi][ni][r] + bv;
        v = fmaxf(v, 0.f);
        C[(size_t)row * N + col] = f2bf(v);
      }
    }
  }
}

// ---------------- fused GEMM3 + geometry ----------------
// Block = 16 batch rows. Full-K 16x64 MFMA tile (w3t [64,2048], cols 50..63 zero),
// then closed-form homography + fold + output entirely in-block. No atomics to
// global, no out3 buffer.

__global__ __launch_bounds__(256) void gemm3_geom(
    const unsigned short* __restrict__ A,   // h2 [8192,2048]
    const unsigned short* __restrict__ Bt,  // w3t [64,2048]
    const float* __restrict__ b3,
    float* __restrict__ outp) {
  __shared__ __align__(16) unsigned short As[16 * 64];
  __shared__ __align__(16) unsigned short Bs[64 * 64];
  __shared__ float s_out3[16 * 64];
  __shared__ float s_bias[64];
  __shared__ float fold[16 * 578];
  const int t = threadIdx.x;
  const int lane = t & 63, wv = t >> 6;
  const int l16 = lane & 15, quad = lane >> 4;
  const int m0 = blockIdx.x * 16;

  if (t < 64) s_bias[t] = (t < 50) ? b3[t] : 0.f;
  for (int i = t; i < 16 * 578; i += 256) fold[i] = 0.f;

  const int srow = lane >> 3;  // 0..7
  const int sg = lane & 7;

  f32x4 acc = {};

  for (int k0 = 0; k0 < 2048; k0 += 64) {
    if (wv < 2) {
      int row = wv * 8 + srow;
      int col = (sg ^ (row & 7)) * 8;
      load16_lds(A + (size_t)(m0 + row) * 2048 + k0 + col, As + wv * 8 * 64);
    }
    #pragma unroll
    for (int r = 0; r < 2; ++r) {
      int row = wv * 16 + r * 8 + srow;
      int col = (sg ^ (row & 7)) * 8;
      load16_lds(Bt + (size_t)row * 2048 + k0 + col, Bs + (wv * 16 + r * 8) * 64);
    }
    __syncthreads();
    #pragma unroll
    for (int half = 0; half < 2; ++half) {
      int apb = (half * 4 + quad) ^ (l16 & 7);
      bf16x8 af = *(const bf16x8*)&As[l16 * 64 + apb * 8];
      int brow = wv * 16 + l16;
      int bpb = (half * 4 + quad) ^ (brow & 7);
      bf16x8 bf = *(const bf16x8*)&Bs[brow * 64 + bpb * 8];
      acc = __builtin_amdgcn_mfma_f32_16x16x32_bf16(af, bf, acc, 0, 0, 0);
    }
    __syncthreads();
  }

  // C/D layout: col = l16 -> m (A rows = batches), row = quad*4+r -> n? No:
  // D[row][col] with row from quad*4+r (M dim of 16x16 tile = A's m), col = l16 (N dim).
  // Here A supplies m (batch 0..15), B supplies n (out3 col, wv*16+l16).
  // value(m = quad*4 + r, n = wv*16 + l16).
  {
    int n = wv * 16 + l16;
    float bv = s_bias[n];
    #pragma unroll
    for (int r = 0; r < 4; ++r)
      s_out3[(quad * 4 + r) * 64 + n] = acc[r] + bv;
  }
  __syncthreads();

  // geometry: 16 batches x 16 patches, 1 thread each
  {
    const int bl = t >> 4;
    const int p = t & 15;
    const int pi = p >> 2, pj = p & 3;
    const float* o = &s_out3[bl * 64];

    float u00 = 128.f * pi       + o[pi * 5 + pj];
    float v00 = 128.f * pj       + o[25 + pi * 5 + pj];
    float u01 = 128.f * pi       + o[pi * 5 + pj + 1];
    float v01 = 128.f * (pj + 1) + o[25 + pi * 5 + pj + 1];
    float u10 = 128.f * (pi + 1) + o[(pi + 1) * 5 + pj];
    float v10 = 128.f * pj       + o[25 + (pi + 1) * 5 + pj];
    float u11 = 128.f * (pi + 1) + o[(pi + 1) * 5 + pj + 1];
    float v11 = 128.f * (pj + 1) + o[25 + (pi + 1) * 5 + pj + 1];

    float sx = u00 - u10 + u11 - u01;
    float sy = v00 - v10 + v11 - v01;
    float dx1 = u10 - u11, dx2 = u01 - u11;
    float dy1 = v10 - v11, dy2 = v01 - v11;
    float rden = 1.f / (dx1 * dy2 - dx2 * dy1);
    float g = (sx * dy2 - dx2 * sy) * rden;
    float h = (dx1 * sy - sx * dy1) * rden;
    float a = u10 - u00 + g * u10;
    float b = u01 - u00 + h * u01;
    float c = u00;
    float d = v10 - v00 + g * v10;
    float e = v01 - v00 + h * v01;
    float f = v00;

    #pragma unroll
    for (int ai = 0; ai < 5; ++ai) {
      #pragma unroll
      for (int bi = 0; bi < 5; ++bi) {
        float s = 0.25f * ai, tt = 0.25f * bi;
        float rw = 1.f / (g * s + h * tt + 1.f);
        float xx = (a * s + b * tt + c) * rw;
        float yy = (d * s + e * tt + f) * rw;
        int gi = pi * 4 + ai, gj = pj * 4 + bi;
        atomicAdd(&fold[(bl * 2 + 0) * 289 + gi * 17 + gj], xx);
        atomicAdd(&fold[(bl * 2 + 1) * 289 + gi * 17 + gj], yy);
      }
    }
  }
  __syncthreads();

  for (int i = t; i < 16 * 578; i += 256) {
    int blb = i / 578;
    int rem = i - blb * 578;
    int ch = rem / 289;
    int ij = rem - ch * 289;
    int gi = ij / 17, gj = ij - gi * 17;
    float val = fold[i];
    if ((gi % 4 == 0) && (gj % 4 == 0)) val *= 0.5f;
    if ((gi == 0 || gi == 16) && (gj == 0 || gj == 16)) val *= 2.f;
    val -= (ch == 0) ? 32.f * gi : 32.f * gj;
    outp[(size_t)(m0 + blb) * 578 + rem] = val;
  }
}

// ---------------- launch ----------------

extern "C" void kernel_launch(void* const* d_in, const int* in_sizes, int n_in,
                              void* d_out, int out_size, void* d_ws, size_t ws_size,
                              hipStream_t stream) {
  const float* x  = (const float*)d_in[0];
  const float* W1 = (const float*)d_in[1];
  const float* b1 = (const float*)d_in[2];
  const float* W2 = (const float*)d_in[3];
  const float* b2 = (const float*)d_in[4];
  const float* W3 = (const float*)d_in[5];
  const float* b3 = (const float*)d_in[6];
  float* outp = (float*)d_out;

  char* ws = (char*)d_ws;
  size_t off = 0;
  auto alloc = [&](size_t bytes) {
    void* pp = ws + off;
    off += (bytes + 255) & ~(size_t)255;
    return pp;
  };
  unsigned short* xbf = (unsigned short*)alloc((size_t)8192 * 1024 * 2);
  unsigned short* w1t = (unsigned short*)alloc((size_t)1024 * 1024 * 2);
  unsigned short* w2t = (unsigned short*)alloc((size_t)2048 * 1024 * 2);
  unsigned short* w3t = (unsigned short*)alloc((size_t)64 * 2048 * 2);
  unsigned short* h1  = (unsigned short*)alloc((size_t)8192 * 1024 * 2);
  unsigned short* h2  = (unsigned short*)alloc((size_t)8192 * 2048 * 2);

  prepass<<<5632, 256, 0, stream>>>(x, W1, W2, W3, xbf, w1t, w2t, w3t);

  gemm_bt_relu_n64<<<dim3(64, 16), 256, 0, stream>>>(xbf, w1t, b1, h1, 1024, 1024);
  gemm_bt_relu<<<dim3(64, 16), 256, 0, stream>>>(h1, w2t, b2, h2, 2048, 1024);
  gemm3_geom<<<512, 256, 0, stream>>>(h2, w3t, b3, outp);
}

// Round 5
// 219.208 us; speedup vs baseline: 1.3444x; 1.0003x over previous
//
#include <hip/hip_runtime.h>

typedef __bf16 bf16x8 __attribute__((ext_vector_type(8)));
typedef float f32x4 __attribute__((ext_vector_type(4)));

__device__ __forceinline__ unsigned short f2bf(float f) {
  unsigned int u = __builtin_bit_cast(unsigned int, f);
  unsigned int r = (u + 0x7fffu + ((u >> 16) & 1u)) >> 16;
  return (unsigned short)r;
}

__device__ __forceinline__ void load16_lds(const unsigned short* g, unsigned short* l) {
  __builtin_amdgcn_global_load_lds(
      (const __attribute__((address_space(1))) void*)g,
      (__attribute__((address_space(3))) void*)l, 16, 0, 0);
}

// ---------------- fused pre-pass: x cvt + W1/W2 transpose + W3t ----------------

__global__ __launch_bounds__(256) void prepass(
    const float* __restrict__ x, const float* __restrict__ W1,
    const float* __restrict__ W2, const float* __restrict__ W3,
    unsigned short* __restrict__ xbf, unsigned short* __restrict__ w1t,
    unsigned short* __restrict__ w2t, unsigned short* __restrict__ w3t) {
  __shared__ float tile[32][33];
  const int bid = blockIdx.x;
  const int t = threadIdx.x;
  if (bid < 2048) {
    for (int i = bid * 256 + t; i < 2097152; i += 2048 * 256) {
      float4 f = ((const float4*)x)[i];
      uint2 o;
      o.x = (unsigned)f2bf(f.x) | ((unsigned)f2bf(f.y) << 16);
      o.y = (unsigned)f2bf(f.z) | ((unsigned)f2bf(f.w) << 16);
      ((uint2*)xbf)[i] = o;
    }
  } else if (bid < 3072) {
    int ti = bid - 2048;
    int n0 = (ti & 31) * 32, k0 = (ti >> 5) * 32;
    int tx = t & 31, ty = t >> 5;
    #pragma unroll
    for (int r = 0; r < 32; r += 8)
      tile[ty + r][tx] = W1[(size_t)(k0 + ty + r) * 1024 + n0 + tx];
    __syncthreads();
    #pragma unroll
    for (int r = 0; r < 32; r += 8)
      w1t[(size_t)(n0 + ty + r) * 1024 + k0 + tx] = f2bf(tile[tx][ty + r]);
  } else if (bid < 5120) {
    int ti = bid - 3072;
    int n0 = (ti & 63) * 32, k0 = (ti >> 6) * 32;
    int tx = t & 31, ty = t >> 5;
    #pragma unroll
    for (int r = 0; r < 32; r += 8)
      tile[ty + r][tx] = W2[(size_t)(k0 + ty + r) * 2048 + n0 + tx];
    __syncthreads();
    #pragma unroll
    for (int r = 0; r < 32; r += 8)
      w2t[(size_t)(n0 + ty + r) * 1024 + k0 + tx] = f2bf(tile[tx][ty + r]);
  } else {
    int idx = (bid - 5120) * 256 + t;
    int n = idx >> 11, k = idx & 2047;
    w3t[idx] = f2bf((n < 50) ? W3[(size_t)k * 50 + n] : 0.f);
  }
}

// ---------------- GEMM (128x128): C = relu(A @ Bt^T + bias) ----------------

__global__ __launch_bounds__(256) void gemm_bt_relu(
    const unsigned short* __restrict__ A,
    const unsigned short* __restrict__ Bt,
    const float* __restrict__ bias,
    unsigned short* __restrict__ C,
    int N, int K) {
  __shared__ __align__(16) unsigned short As[128 * 64];
  __shared__ __align__(16) unsigned short Bs[128 * 64];
  const int t = threadIdx.x;
  const int m0 = blockIdx.x * 128;
  const int n0 = blockIdx.y * 128;
  const int lane = t & 63, wv = t >> 6;
  const int l16 = lane & 15, quad = lane >> 4;
  const int wm = (wv >> 1) * 64, wn = (wv & 1) * 64;

  const int srow = t >> 3;
  const int scol = ((t & 7) ^ (srow & 7)) * 8;
  const unsigned short* Ag0 = A + (size_t)(m0 + srow) * K + scol;
  const unsigned short* Bg0 = Bt + (size_t)(n0 + srow) * K + scol;
  unsigned short* AsW = As + wv * 8 * 64;
  unsigned short* BsW = Bs + wv * 8 * 64;

  f32x4 acc[4][4] = {};

  for (int k0 = 0; k0 < K; k0 += 64) {
    #pragma unroll
    for (int r = 0; r < 4; ++r) {
      load16_lds(Ag0 + (size_t)(r * 32) * K + k0, AsW + r * 32 * 64);
      load16_lds(Bg0 + (size_t)(r * 32) * K + k0, BsW + r * 32 * 64);
    }
    __syncthreads();
    #pragma unroll
    for (int half = 0; half < 2; ++half) {
      bf16x8 af[4], bfr[4];
      #pragma unroll
      for (int mi = 0; mi < 4; ++mi) {
        int row = wm + mi * 16 + l16;
        int pb = (half * 4 + quad) ^ (row & 7);
        af[mi] = *(const bf16x8*)&As[row * 64 + pb * 8];
      }
      #pragma unroll
      for (int ni = 0; ni < 4; ++ni) {
        int row = wn + ni * 16 + l16;
        int pb = (half * 4 + quad) ^ (row & 7);
        bfr[ni] = *(const bf16x8*)&Bs[row * 64 + pb * 8];
      }
      #pragma unroll
      for (int mi = 0; mi < 4; ++mi)
        #pragma unroll
        for (int ni = 0; ni < 4; ++ni)
          acc[mi][ni] = __builtin_amdgcn_mfma_f32_16x16x32_bf16(
              af[mi], bfr[ni], acc[mi][ni], 0, 0, 0);
    }
    __syncthreads();
  }

  #pragma unroll
  for (int mi = 0; mi < 4; ++mi) {
    #pragma unroll
    for (int ni = 0; ni < 4; ++ni) {
      int col = n0 + wn + ni * 16 + l16;
      float bv = bias[col];
      #pragma unroll
      for (int r = 0; r < 4; ++r) {
        int row = m0 + wm + mi * 16 + quad * 4 + r;
        float v = acc[mi][ni][r] + bv;
        v = fmaxf(v, 0.f);
        C[(size_t)row * N + col] = f2bf(v);
      }
    }
  }
}

// ---------------- GEMM (128x64 n-tile) for GEMM1 ----------------

__global__ __launch_bounds__(256) void gemm_bt_relu_n64(
    const unsigned short* __restrict__ A,
    const unsigned short* __restrict__ Bt,
    const float* __restrict__ bias,
    unsigned short* __restrict__ C,
    int N, int K) {
  __shared__ __align__(16) unsigned short As[128 * 64];
  __shared__ __align__(16) unsigned short Bs[64 * 64];
  const int t = threadIdx.x;
  const int m0 = blockIdx.x * 128;
  const int n0 = blockIdx.y * 64;
  const int lane = t & 63, wv = t >> 6;
  const int l16 = lane & 15, quad = lane >> 4;
  const int wm = (wv >> 1) * 64, wn = (wv & 1) * 32;

  const int srow = t >> 3;
  const int scol = ((t & 7) ^ (srow & 7)) * 8;
  const unsigned short* Ag0 = A + (size_t)(m0 + srow) * K + scol;
  const unsigned short* Bg0 = Bt + (size_t)(n0 + srow) * K + scol;
  unsigned short* AsW = As + wv * 8 * 64;
  unsigned short* BsW = Bs + wv * 8 * 64;

  f32x4 acc[4][2] = {};

  for (int k0 = 0; k0 < K; k0 += 64) {
    #pragma unroll
    for (int r = 0; r < 4; ++r)
      load16_lds(Ag0 + (size_t)(r * 32) * K + k0, AsW + r * 32 * 64);
    #pragma unroll
    for (int r = 0; r < 2; ++r)
      load16_lds(Bg0 + (size_t)(r * 32) * K + k0, BsW + r * 32 * 64);
    __syncthreads();
    #pragma unroll
    for (int half = 0; half < 2; ++half) {
      bf16x8 af[4], bfr[2];
      #pragma unroll
      for (int mi = 0; mi < 4; ++mi) {
        int row = wm + mi * 16 + l16;
        int pb = (half * 4 + quad) ^ (row & 7);
        af[mi] = *(const bf16x8*)&As[row * 64 + pb * 8];
      }
      #pragma unroll
      for (int ni = 0; ni < 2; ++ni) {
        int row = wn + ni * 16 + l16;
        int pb = (half * 4 + quad) ^ (row & 7);
        bfr[ni] = *(const bf16x8*)&Bs[row * 64 + pb * 8];
      }
      #pragma unroll
      for (int mi = 0; mi < 4; ++mi)
        #pragma unroll
        for (int ni = 0; ni < 2; ++ni)
          acc[mi][ni] = __builtin_amdgcn_mfma_f32_16x16x32_bf16(
              af[mi], bfr[ni], acc[mi][ni], 0, 0, 0);
    }
    __syncthreads();
  }

  #pragma unroll
  for (int mi = 0; mi < 4; ++mi) {
    #pragma unroll
    for (int ni = 0; ni < 2; ++ni) {
      int col = n0 + wn + ni * 16 + l16;
      float bv = bias[col];
      #pragma unroll
      for (int r = 0; r < 4; ++r) {
        int row = m0 + wm + mi * 16 + quad * 4 + r;
        float v = acc[mi][ni][r] + bv;
        v = fmaxf(v, 0.f);
        C[(size_t)row * N + col] = f2bf(v);
      }
    }
  }
}

// ---------------- GEMM3 partials: part[kz][8192][64] = h2[:,kz*512:+512] @ w3t^T ----
// Grid (64 m, 4 kz). 128x64 tile, 8 iterations of BK=64. No atomics.

__global__ __launch_bounds__(256) void gemm3_part(
    const unsigned short* __restrict__ A,   // h2 [8192,2048]
    const unsigned short* __restrict__ Bt,  // w3t [64,2048]
    float* __restrict__ part) {
  __shared__ __align__(16) unsigned short As[128 * 64];
  __shared__ __align__(16) unsigned short Bs[64 * 64];
  const int t = threadIdx.x;
  const int m0 = blockIdx.x * 128;
  const int kz = blockIdx.y;
  const int lane = t & 63, wv = t >> 6;
  const int l16 = lane & 15, quad = lane >> 4;
  const int wm = (wv >> 1) * 64, wn = (wv & 1) * 32;

  const int srow = t >> 3;
  const int scol = ((t & 7) ^ (srow & 7)) * 8;
  const unsigned short* Ag0 = A + (size_t)(m0 + srow) * 2048 + kz * 512 + scol;
  const unsigned short* Bg0 = Bt + (size_t)srow * 2048 + kz * 512 + scol;
  unsigned short* AsW = As + wv * 8 * 64;
  unsigned short* BsW = Bs + wv * 8 * 64;

  f32x4 acc[4][2] = {};

  for (int k0 = 0; k0 < 512; k0 += 64) {
    #pragma unroll
    for (int r = 0; r < 4; ++r)
      load16_lds(Ag0 + (size_t)(r * 32) * 2048 + k0, AsW + r * 32 * 64);
    #pragma unroll
    for (int r = 0; r < 2; ++r)
      load16_lds(Bg0 + (size_t)(r * 32) * 2048 + k0, BsW + r * 32 * 64);
    __syncthreads();
    #pragma unroll
    for (int half = 0; half < 2; ++half) {
      bf16x8 af[4], bfr[2];
      #pragma unroll
      for (int mi = 0; mi < 4; ++mi) {
        int row = wm + mi * 16 + l16;
        int pb = (half * 4 + quad) ^ (row & 7);
        af[mi] = *(const bf16x8*)&As[row * 64 + pb * 8];
      }
      #pragma unroll
      for (int ni = 0; ni < 2; ++ni) {
        int row = wn + ni * 16 + l16;
        int pb = (half * 4 + quad) ^ (row & 7);
        bfr[ni] = *(const bf16x8*)&Bs[row * 64 + pb * 8];
      }
      #pragma unroll
      for (int mi = 0; mi < 4; ++mi)
        #pragma unroll
        for (int ni = 0; ni < 2; ++ni)
          acc[mi][ni] = __builtin_amdgcn_mfma_f32_16x16x32_bf16(
              af[mi], bfr[ni], acc[mi][ni], 0, 0, 0);
    }
    __syncthreads();
  }

  float* pbase = part + (size_t)kz * 8192 * 64;
  #pragma unroll
  for (int mi = 0; mi < 4; ++mi) {
    #pragma unroll
    for (int ni = 0; ni < 2; ++ni) {
      int col = wn + ni * 16 + l16;
      #pragma unroll
      for (int r = 0; r < 4; ++r) {
        int row = m0 + wm + mi * 16 + quad * 4 + r;
        pbase[(size_t)row * 64 + col] = acc[mi][ni][r];
      }
    }
  }
}

// ---------------- geometry + partial reduction ----------------
// 512 blocks x 16 batches. Sum 4 partials + bias -> s_out3, then homography+fold.

__global__ __launch_bounds__(256) void geom_reduce(
    const float* __restrict__ part, const float* __restrict__ b3,
    float* __restrict__ outp) {
  __shared__ float s_out3[16 * 64];
  __shared__ float fold[16 * 578];
  const int t = threadIdx.x;
  const int bbase = blockIdx.x * 16;

  for (int i = t; i < 16 * 578; i += 256) fold[i] = 0.f;
  // reduce partials: 16 batches x 64 cols = 1024 values, 4 per thread
  for (int i = t; i < 1024; i += 256) {
    int m = i >> 6, n = i & 63;
    size_t idx = (size_t)(bbase + m) * 64 + n;
    float v = part[idx] + part[idx + (size_t)8192 * 64]
            + part[idx + (size_t)2 * 8192 * 64] + part[idx + (size_t)3 * 8192 * 64];
    s_out3[i] = v + ((n < 50) ? b3[n] : 0.f);
  }
  __syncthreads();

  {
    const int bl = t >> 4;
    const int p = t & 15;
    const int pi = p >> 2, pj = p & 3;
    const float* o = &s_out3[bl * 64];

    float u00 = 128.f * pi       + o[pi * 5 + pj];
    float v00 = 128.f * pj       + o[25 + pi * 5 + pj];
    float u01 = 128.f * pi       + o[pi * 5 + pj + 1];
    float v01 = 128.f * (pj + 1) + o[25 + pi * 5 + pj + 1];
    float u10 = 128.f * (pi + 1) + o[(pi + 1) * 5 + pj];
    float v10 = 128.f * pj       + o[25 + (pi + 1) * 5 + pj];
    float u11 = 128.f * (pi + 1) + o[(pi + 1) * 5 + pj + 1];
    float v11 = 128.f * (pj + 1) + o[25 + (pi + 1) * 5 + pj + 1];

    float sx = u00 - u10 + u11 - u01;
    float sy = v00 - v10 + v11 - v01;
    float dx1 = u10 - u11, dx2 = u01 - u11;
    float dy1 = v10 - v11, dy2 = v01 - v11;
    float rden = 1.f / (dx1 * dy2 - dx2 * dy1);
    float g = (sx * dy2 - dx2 * sy) * rden;
    float h = (dx1 * sy - sx * dy1) * rden;
    float a = u10 - u00 + g * u10;
    float b = u01 - u00 + h * u01;
    float c = u00;
    float d = v10 - v00 + g * v10;
    float e = v01 - v00 + h * v01;
    float f = v00;

    #pragma unroll
    for (int ai = 0; ai < 5; ++ai) {
      #pragma unroll
      for (int bi = 0; bi < 5; ++bi) {
        float s = 0.25f * ai, tt = 0.25f * bi;
        float rw = 1.f / (g * s + h * tt + 1.f);
        float xx = (a * s + b * tt + c) * rw;
        float yy = (d * s + e * tt + f) * rw;
        int gi = pi * 4 + ai, gj = pj * 4 + bi;
        atomicAdd(&fold[(bl * 2 + 0) * 289 + gi * 17 + gj], xx);
        atomicAdd(&fold[(bl * 2 + 1) * 289 + gi * 17 + gj], yy);
      }
    }
  }
  __syncthreads();

  for (int i = t; i < 16 * 578; i += 256) {
    int blb = i / 578;
    int rem = i - blb * 578;
    int ch = rem / 289;
    int ij = rem - ch * 289;
    int gi = ij / 17, gj = ij - gi * 17;
    float val = fold[i];
    if ((gi % 4 == 0) && (gj % 4 == 0)) val *= 0.5f;
    if ((gi == 0 || gi == 16) && (gj == 0 || gj == 16)) val *= 2.f;
    val -= (ch == 0) ? 32.f * gi : 32.f * gj;
    outp[(size_t)(bbase + blb) * 578 + rem] = val;
  }
}

// ---------------- launch ----------------

extern "C" void kernel_launch(void* const* d_in, const int* in_sizes, int n_in,
                              void* d_out, int out_size, void* d_ws, size_t ws_size,
                              hipStream_t stream) {
  const float* x  = (const float*)d_in[0];
  const float* W1 = (const float*)d_in[1];
  const float* b1 = (const float*)d_in[2];
  const float* W2 = (const float*)d_in[3];
  const float* b2 = (const float*)d_in[4];
  const float* W3 = (const float*)d_in[5];
  const float* b3 = (const float*)d_in[6];
  float* outp = (float*)d_out;

  char* ws = (char*)d_ws;
  size_t off = 0;
  auto alloc = [&](size_t bytes) {
    void* pp = ws + off;
    off += (bytes + 255) & ~(size_t)255;
    return pp;
  };
  unsigned short* xbf = (unsigned short*)alloc((size_t)8192 * 1024 * 2);
  unsigned short* w1t = (unsigned short*)alloc((size_t)1024 * 1024 * 2);
  unsigned short* w2t = (unsigned short*)alloc((size_t)2048 * 1024 * 2);
  unsigned short* w3t = (unsigned short*)alloc((size_t)64 * 2048 * 2);
  unsigned short* h1  = (unsigned short*)alloc((size_t)8192 * 1024 * 2);
  unsigned short* h2  = (unsigned short*)alloc((size_t)8192 * 2048 * 2);
  float* part = (float*)alloc((size_t)4 * 8192 * 64 * 4);

  prepass<<<5632, 256, 0, stream>>>(x, W1, W2, W3, xbf, w1t, w2t, w3t);

  gemm_bt_relu_n64<<<dim3(64, 16), 256, 0, stream>>>(xbf, w1t, b1, h1, 1024, 1024);
  gemm_bt_relu<<<dim3(64, 16), 256, 0, stream>>>(h1, w2t, b2, h2, 2048, 1024);
  gemm3_part<<<dim3(64, 4), 256, 0, stream>>>(h2, w3t, part);
  geom_reduce<<<512, 256, 0, stream>>>(part, b3, outp);
}